// Round 5
// baseline (172.500 us; speedup 1.0000x reference)
//
#include <hip/hip_runtime.h>
#include <math.h>

// InfoNCE loss, K=3, SKIP=1, NEG=64
// z,c: (64,256,14,14) f32; Wk: (3,256,256) f32; neg_idx_k: (rows_k*64,) i32
// rows_k = 10752, 9856, 8960. row = (h*14+w)*64 + b.
//
// Pipeline (4 launches): prep (casts+transposes+zero; ct8 written in
// fragment-major permuted layout), proj (LDS-staged bf16 MFMA GEMM -> ztwk
// fp8 in fragment-major permuted layout), loss (REGISTER-GATHER: one wave
// per row, no LDS, no barriers; A/B MFMA fragments loaded directly from
// global as 4x dwordx4 per tile thanks to the permuted layout; deferred
// one-pass softmax), reduce.
//
// Fragment-major permutation P (bijective bit shuffle of the 256-B row):
//   orig byte o = kk*32 + kq*8 + t   (kk=0..7, kq=0..3, t=0..7)
//   new  byte n = (kk>>1)*64 + kq*16 + (kk&1)*8 + t
// Lane (m,kq) fragment chunk c (c=kk>>1) = 16 B at n = c*64 + kq*16; the 4
// kq-lanes of one slot-row cover a contiguous 64-B sector per load instr.

typedef short bf16x8 __attribute__((ext_vector_type(8)));
typedef float f32x4 __attribute__((ext_vector_type(4)));
typedef long long ll2 __attribute__((ext_vector_type(2)));

static __device__ __forceinline__ unsigned short f2bf(float f) {
    union { float f; unsigned int u; } x; x.f = f;
    unsigned int r = x.u + 0x7fffu + ((x.u >> 16) & 1u);   // RNE
    return (unsigned short)(r >> 16);
}

// float -> OCP e4m3fn (RNE, saturate to 448, subnormals handled)
static __device__ __forceinline__ unsigned char f2e4m3(float f) {
    union { float f; unsigned int u; } x; x.f = f;
    unsigned int s = (x.u >> 24) & 0x80u;
    float af = fabsf(f);
    if (af > 448.f) af = 448.f;
    x.f = af;
    unsigned int u = x.u;
    int e = (int)(u >> 23) - 127;
    unsigned int out;
    if (af == 0.f) {
        out = 0u;
    } else if (e < -6) {
        int mq = (int)rintf(af * 512.f);          // multiples of 2^-9
        out = (mq >= 8) ? 0x08u : (unsigned int)mq;
    } else {
        unsigned int r = u + 0x7FFFFu + ((u >> 20) & 1u);  // RNE, drop 20 bits
        int e2 = (int)(r >> 23) - 127;
        if (e2 > 8) out = 0x7Eu;                  // 448
        else out = (unsigned int)(((e2 + 7) << 3) | ((r >> 20) & 7u));
    }
    return (unsigned char)(s | out);
}

// prep: blocks [0,768): Wk->bf16 (block0 also zeroes out[0]);
// [768,1792): z -> zt bf16 transposed; [1792,2816): c -> ct8 fp8 transposed
// into the fragment-major permuted layout.
__global__ __launch_bounds__(256)
void prep_kernel(const float* __restrict__ z, const float* __restrict__ c,
                 const float* __restrict__ Wk,
                 unsigned short* __restrict__ zt, unsigned char* __restrict__ ct8,
                 unsigned short* __restrict__ wkb, float* __restrict__ out) {
    __shared__ float tile[16][201];
    const int tid = threadIdx.x;
    int x = blockIdx.x;
    if (x < 768) {
        int i = x * 256 + tid;
        wkb[i] = f2bf(Wk[i]);
        if (x == 0 && tid == 0) out[0] = 0.f;
        return;
    }
    const bool isz = x < 1792;
    const int local = isz ? (x - 768) : (x - 1792);
    const float* src = isz ? z : c;
    const int b  = local & 63;
    const int c0 = (local >> 6) << 4;
    for (int i = tid; i < 16 * 196; i += 256) {
        int cc = i / 196;
        int hw = i - cc * 196;
        tile[cc][hw] = src[(size_t)((b << 8) + c0 + cc) * 196 + hw];
    }
    __syncthreads();
    if (isz) {
        for (int i = tid; i < 196 * 16; i += 256) {
            int hw = i >> 4, cc = i & 15;
            zt[(size_t)((hw << 6) + b) * 256 + c0 + cc] = f2bf(tile[cc][hw]);
        }
    } else {
        for (int i = tid; i < 196 * 16; i += 256) {
            int hw = i >> 4, cc = i & 15;
            int o = c0 + cc;
            int n = ((o >> 6) << 6) | (((o >> 3) & 3) << 4)
                  | (((o >> 5) & 1) << 3) | (o & 7);          // P(o)
            ct8[(size_t)((hw << 6) + b) * 256 + n] = f2e4m3(tile[cc][hw]);
        }
    }
}

// proj: ztwk8[k][row][P(o)] = fp8(sum_c zt[zrow][c] * wk[k][o][c])
// Grid (8, 462): o-tile is blockIdx.x (FAST) so the 8 o-tiles of one hw-tile
// dispatch consecutively -> A tile stays L2-hot. Tile M=64 x N=32. PSTR 528.
#define PSTR 528
__global__ __launch_bounds__(256)
void proj_mfma_kernel(const unsigned short* __restrict__ zt,
                      const unsigned short* __restrict__ wkb,
                      unsigned char* __restrict__ ztwk) {
    __shared__ __align__(16) unsigned char smem[(64 + 32) * PSTR];  // 50688 B
    unsigned char* smA = smem;
    unsigned char* smB = smem + 64 * PSTR;

    int x = blockIdx.y;
    int k, hw;
    if (x < 168)      { k = 0; hw = x; }
    else if (x < 322) { k = 1; hw = x - 168; }
    else              { k = 2; hw = x - 322; }
    const int o0 = blockIdx.x << 5;                    // 32 outs per block
    const int row0  = hw << 6;
    const int zrow0 = row0 + (((k + 2) * 14) << 6);    // h' = h + (k_idx+2)
    unsigned char* zo = ztwk + (size_t)k * 10752 * 256;

    const int tid = threadIdx.x;
    const unsigned char* zsrc = (const unsigned char*)(zt + (size_t)zrow0 * 256);
    const unsigned char* bsrc = (const unsigned char*)(wkb + ((size_t)k << 16) + o0 * 256);

    #pragma unroll
    for (int i = 0; i < 8; ++i) {          // A: 32 KB contiguous
        int sb = ((i << 8) + tid) << 4;
        int r = sb >> 9, off = sb & 511;
        *(int4*)(smA + r * PSTR + off) = *(const int4*)(zsrc + sb);
    }
    #pragma unroll
    for (int i = 0; i < 4; ++i) {          // B: 16 KB contiguous
        int sb = ((i << 8) + tid) << 4;
        int r = sb >> 9, off = sb & 511;
        *(int4*)(smB + r * PSTR + off) = *(const int4*)(bsrc + sb);
    }
    __syncthreads();

    const int wv = tid >> 6, lane = tid & 63;
    const int m = lane & 15, kq = lane >> 4;
    f32x4 acc[2] = {};
    const unsigned short* aP  = (const unsigned short*)(smA + (size_t)((wv << 4) + m) * PSTR) + (kq << 3);
    const unsigned short* bP0 = (const unsigned short*)(smB + (size_t)m * PSTR) + (kq << 3);
    const unsigned short* bP1 = (const unsigned short*)(smB + (size_t)(16 + m) * PSTR) + (kq << 3);
    #pragma unroll
    for (int kk = 0; kk < 256; kk += 32) {
        bf16x8 af = *(const bf16x8*)(aP  + kk);
        bf16x8 b0 = *(const bf16x8*)(bP0 + kk);
        bf16x8 b1 = *(const bf16x8*)(bP1 + kk);
        acc[0] = __builtin_amdgcn_mfma_f32_16x16x32_bf16(af, b0, acc[0], 0, 0, 0);
        acc[1] = __builtin_amdgcn_mfma_f32_16x16x32_bf16(af, b1, acc[1], 0, 0, 0);
    }
    __syncthreads();
    unsigned char* cs = smA;               // [64 rows][40 B]
    #pragma unroll
    for (int nt = 0; nt < 2; ++nt)
        #pragma unroll
        for (int r = 0; r < 4; ++r)
            cs[(size_t)((wv << 4) + (kq << 2) + r) * 40 + (nt << 4) + m] =
                f2e4m3(acc[nt][r]);
    __syncthreads();
    {
        // 8-B chunk = channels o = o0 + off + t (t=0..7). Under P:
        // kk = bx, kq = off>>3 -> n0 = (bx>>1)*64 + (off>>3)*16 + (bx&1)*8.
        int r = tid >> 2, off = (tid & 3) << 3;
        unsigned long long v = *(const unsigned long long*)(cs + (size_t)r * 40 + off);
        *(unsigned long long*)(zo + (size_t)(row0 + r) * 256
            + ((blockIdx.x >> 1) << 6) + (off << 1) + ((blockIdx.x & 1) << 3)) = v;
    }
}

// ---------------------------------------------------------------------------
// loss: register-gather, one wave per row. 29568 rows = 7392 blocks x 4
// independent waves (no barriers, no LDS). Slots: 0 main, 1..64 negs, tile
// t=0..3 covers slots 16t..16t+15, tail tile 4 = slot 64 broadcast to all
// A rows (every acc[4][r] equals the slot-64 score; counted once via kq==0
// mask). Per tile: 4x dwordx4 per lane (fragment-major layout). Deferred
// one-pass softmax over 5 accumulators.
// ---------------------------------------------------------------------------
static __device__ __forceinline__ void rowmeta(int gr, int* k, int* row) {
    if (gr < 10752)      { *k = 0; *row = gr; }
    else if (gr < 20608) { *k = 1; *row = gr - 10752; }
    else                 { *k = 2; *row = gr - 20608; }
}

__global__ __launch_bounds__(256, 4)
void loss_mfma_kernel(const unsigned char* __restrict__ ct8,
                      const unsigned char* __restrict__ ztwk8,
                      const int* __restrict__ n0, const int* __restrict__ n1,
                      const int* __restrict__ n2, float* __restrict__ rowloss) {
    const int tid = threadIdx.x;
    const int wv = tid >> 6, lane = tid & 63;
    const int m = lane & 15, kq = lane >> 4;
    const int gr = (blockIdx.x << 2) + wv;            // 0..29567
    int k, row; rowmeta(gr, &k, &row);
    const int* nb = (k == 0) ? n0 : (k == 1) ? n1 : n2;
    const float wkc = (k == 0) ? (1.f / (3.f * 10752.f))
                    : (k == 1) ? (1.f / (3.f * 9856.f))
                               : (1.f / (3.f * 8960.f));
    const unsigned char* f8 = ztwk8 + (size_t)k * 10752 * 256;

    const int myidx = nb[((size_t)row << 6) + lane];  // coalesced 256 B

    // B fragments: ctx row (permuted ct8), 4x dwordx4 per lane
    long long bf[8];
    {
        const unsigned char* cb = ct8 + (size_t)row * 256 + (kq << 4);
        #pragma unroll
        for (int c = 0; c < 4; ++c) {
            ll2 v = *(const ll2*)(cb + (c << 6));
            bf[2 * c] = v.x; bf[2 * c + 1] = v.y;
        }
    }

    // slot-rows per tile: slot s = 16t + m; s==0 -> main row; s>64 -> 64
    int sr[5];
    #pragma unroll
    for (int t = 0; t < 5; ++t) {
        int s = (t << 4) + m; if (s > 64) s = 64;
        int sel = s - 1; if (sel < 0) sel = 0;
        int v = __shfl(myidx, sel);
        sr[t] = (s == 0) ? row : v;
    }

    // A fragments: 4x dwordx4 per lane per tile; 2-tile lookahead
    long long af[5][8];
    #pragma unroll
    for (int t = 0; t < 2; ++t) {
        const unsigned char* p = f8 + (size_t)sr[t] * 256 + (kq << 4);
        #pragma unroll
        for (int c = 0; c < 4; ++c) {
            ll2 v = *(const ll2*)(p + (c << 6));
            af[t][2 * c] = v.x; af[t][2 * c + 1] = v.y;
        }
    }

    f32x4 acc[5];
    #pragma unroll
    for (int t = 0; t < 5; ++t) {
        if (t + 2 < 5) {
            const unsigned char* p = f8 + (size_t)sr[t + 2] * 256 + (kq << 4);
            #pragma unroll
            for (int c = 0; c < 4; ++c) {
                ll2 v = *(const ll2*)(p + (c << 6));
                af[t + 2][2 * c] = v.x; af[t + 2][2 * c + 1] = v.y;
            }
        }
        f32x4 a = {0.f, 0.f, 0.f, 0.f};
        #pragma unroll
        for (int kk = 0; kk < 8; ++kk)
            a = __builtin_amdgcn_mfma_f32_16x16x32_fp8_fp8(af[t][kk], bf[kk], a, 0, 0, 0);
        acc[t] = a;
    }

    // deferred one-pass softmax. acc[t][r] = slot (16t + 4kq + r) score
    // (replicated across the 16 m-lanes); reduce across kq via xor16/32.
    float m_l = -1e30f;
    #pragma unroll
    for (int t = 0; t < 4; ++t)
        #pragma unroll
        for (int r = 0; r < 4; ++r) m_l = fmaxf(m_l, acc[t][r]);
    if (kq == 0) m_l = fmaxf(m_l, acc[4][0]);
    m_l = fmaxf(m_l, __shfl_xor(m_l, 16));
    m_l = fmaxf(m_l, __shfl_xor(m_l, 32));

    float s_l = 0.f;
    #pragma unroll
    for (int t = 0; t < 4; ++t)
        #pragma unroll
        for (int r = 0; r < 4; ++r) s_l += __expf(acc[t][r] - m_l);
    if (kq == 0) s_l += __expf(acc[4][0] - m_l);
    s_l += __shfl_xor(s_l, 16);
    s_l += __shfl_xor(s_l, 32);

    float mainl = __shfl(acc[0][0], 0);               // slot 0 (lane 0: kq=0)
    if (lane == 0)
        rowloss[gr] = -logf(__expf(mainl - m_l) / s_l + 1e-11f) * wkc;
}

// Sum rowloss[0..29568) -> out[0] (out zeroed in prep)
__global__ __launch_bounds__(256)
void reduce_kernel(const float* __restrict__ rl, float* __restrict__ out) {
    float s = 0.f;
    const int stride = gridDim.x * blockDim.x;
    for (int i = blockIdx.x * blockDim.x + threadIdx.x; i < 29568; i += stride)
        s += rl[i];
    #pragma unroll
    for (int off = 32; off >= 1; off >>= 1) s += __shfl_xor(s, off);
    if ((threadIdx.x & 63) == 0) atomicAdd(out, s);
}

extern "C" void kernel_launch(void* const* d_in, const int* in_sizes, int n_in,
                              void* d_out, int out_size, void* d_ws, size_t ws_size,
                              hipStream_t stream) {
    const float* z  = (const float*)d_in[0];
    const float* c  = (const float*)d_in[1];
    const float* Wk = (const float*)d_in[2];
    const int* negs[3] = {(const int*)d_in[3], (const int*)d_in[4], (const int*)d_in[5]};
    float* out = (float*)d_out;

    char* p = (char*)d_ws;
    unsigned short* zt      = (unsigned short*)p;   p += (size_t)196 * 64 * 256 * 2;
    unsigned short* wkb     = (unsigned short*)p;   p += (size_t)3 * 65536 * 2;
    unsigned char*  ct8     = (unsigned char*)p;    p += (size_t)196 * 64 * 256;
    unsigned char*  ztwk8   = (unsigned char*)p;    p += (size_t)3 * 10752 * 256;
    float*          rowloss = (float*)p;

    prep_kernel<<<2816, 256, 0, stream>>>(z, c, Wk, zt, ct8, wkb, out);
    proj_mfma_kernel<<<dim3(8, 462), 256, 0, stream>>>(zt, wkb, ztwk8);
    loss_mfma_kernel<<<7392, 256, 0, stream>>>(ct8, ztwk8, negs[0], negs[1],
                                               negs[2], rowloss);
    reduce_kernel<<<32, 256, 0, stream>>>(rowloss, out);
}

// Round 6
// 152.984 us; speedup vs baseline: 1.1276x; 1.1276x over previous
//
#include <hip/hip_runtime.h>
#include <math.h>

// InfoNCE loss, K=3, SKIP=1, NEG=64
// z,c: (64,256,14,14) f32; Wk: (3,256,256) f32; neg_idx_k: (rows_k*64,) i32
// rows_k = 10752, 9856, 8960. row = (h*14+w)*64 + b.
//
// Pipeline (4 launches): prep (casts+transposes+zero; z/c path LDS-free:
// coalesced strided loads + register transpose + WIDE stores -- the old
// version issued 3136 scalar 1-2B stores per block), proj (LDS-staged bf16
// MFMA GEMM -> ztwk fp8, verbatim-verified), loss (R2-verbatim wide-DMA
// gather: 19 VMEM/row, both-sides XOR swizzle; ~48.5us, pinned by the
// shared scattered-gather service rate -- 4 structurally different
// implementations all land 50+-8us with no CU-side counter saturated),
// reduce.

typedef short bf16x8 __attribute__((ext_vector_type(8)));
typedef float f32x4 __attribute__((ext_vector_type(4)));

static __device__ __forceinline__ unsigned short f2bf(float f) {
    union { float f; unsigned int u; } x; x.f = f;
    unsigned int r = x.u + 0x7fffu + ((x.u >> 16) & 1u);   // RNE
    return (unsigned short)(r >> 16);
}

// float -> OCP e4m3fn (RNE, saturate to 448, subnormals handled)
static __device__ __forceinline__ unsigned char f2e4m3(float f) {
    union { float f; unsigned int u; } x; x.f = f;
    unsigned int s = (x.u >> 24) & 0x80u;
    float af = fabsf(f);
    if (af > 448.f) af = 448.f;
    x.f = af;
    unsigned int u = x.u;
    int e = (int)(u >> 23) - 127;
    unsigned int out;
    if (af == 0.f) {
        out = 0u;
    } else if (e < -6) {
        int mq = (int)rintf(af * 512.f);          // multiples of 2^-9
        out = (mq >= 8) ? 0x08u : (unsigned int)mq;
    } else {
        unsigned int r = u + 0x7FFFFu + ((u >> 20) & 1u);  // RNE, drop 20 bits
        int e2 = (int)(r >> 23) - 127;
        if (e2 > 8) out = 0x7Eu;                  // 448
        else out = (unsigned int)(((e2 + 7) << 3) | ((r >> 20) & 7u));
    }
    return (unsigned char)(s | out);
}

// async global->LDS DMA: per-lane global addr, dest = uniform base + lane*sz
static __device__ __forceinline__ void gload_lds4(const void* g, void* l) {
    __builtin_amdgcn_global_load_lds(
        (const __attribute__((address_space(1))) void*)g,
        (__attribute__((address_space(3))) void*)l, 4, 0, 0);
}
static __device__ __forceinline__ void gload_lds16(const void* g, void* l) {
    __builtin_amdgcn_global_load_lds(
        (const __attribute__((address_space(1))) void*)g,
        (__attribute__((address_space(3))) void*)l, 16, 0, 0);
}

// prep: blocks [0,768): Wk->bf16 (block0 also zeroes out[0]);
// [768,1792): z -> zt bf16 transposed; [1792,2816): c -> ct8 fp8 transposed.
// z/c path: thread hw (0..195) loads 16 channels via lane-coalesced dword
// loads (stride 784B between channels, lanes contiguous), packs in regs,
// stores 16 channels per row as wide 16-B stores. No LDS, no barrier.
__global__ __launch_bounds__(256)
void prep_kernel(const float* __restrict__ z, const float* __restrict__ c,
                 const float* __restrict__ Wk,
                 unsigned short* __restrict__ zt, unsigned char* __restrict__ ct8,
                 unsigned short* __restrict__ wkb, float* __restrict__ out) {
    const int tid = threadIdx.x;
    int x = blockIdx.x;
    if (x < 768) {
        int i = x * 256 + tid;
        wkb[i] = f2bf(Wk[i]);
        if (x == 0 && tid == 0) out[0] = 0.f;
        return;
    }
    const bool isz = x < 1792;
    const int local = isz ? (x - 768) : (x - 1792);
    const float* src = isz ? z : c;
    const int b  = local & 63;
    const int c0 = (local >> 6) << 4;
    if (tid >= 196) return;
    const int hw = tid;

    float v[16];
    #pragma unroll
    for (int cc = 0; cc < 16; ++cc)
        v[cc] = src[(size_t)((b << 8) + c0 + cc) * 196 + hw];

    if (isz) {
        union { unsigned short u[16]; int4 q[2]; } pk;
        #pragma unroll
        for (int cc = 0; cc < 16; ++cc) pk.u[cc] = f2bf(v[cc]);
        unsigned short* dst = zt + (size_t)((hw << 6) + b) * 256 + c0;
        *(int4*)(dst)     = pk.q[0];
        *(int4*)(dst + 8) = pk.q[1];
    } else {
        union { unsigned char u[16]; int4 q; } pk;
        #pragma unroll
        for (int cc = 0; cc < 16; ++cc) pk.u[cc] = f2e4m3(v[cc]);
        *(int4*)(ct8 + (size_t)((hw << 6) + b) * 256 + c0) = pk.q;
    }
}

// proj: ztwk8[k][row][o] = fp8(sum_c zt[zrow][c] * wk[k][o][c])
// Grid (8, 462): o-tile is blockIdx.x (FAST) so the 8 o-tiles of one hw-tile
// dispatch consecutively -> A tile stays L2-hot. Tile M=64 x N=32. PSTR 528.
#define PSTR 528
__global__ __launch_bounds__(256)
void proj_mfma_kernel(const unsigned short* __restrict__ zt,
                      const unsigned short* __restrict__ wkb,
                      unsigned char* __restrict__ ztwk) {
    __shared__ __align__(16) unsigned char smem[(64 + 32) * PSTR];  // 50688 B
    unsigned char* smA = smem;
    unsigned char* smB = smem + 64 * PSTR;

    int x = blockIdx.y;
    int k, hw;
    if (x < 168)      { k = 0; hw = x; }
    else if (x < 322) { k = 1; hw = x - 168; }
    else              { k = 2; hw = x - 322; }
    const int o0 = blockIdx.x << 5;                    // 32 outs per block
    const int row0  = hw << 6;
    const int zrow0 = row0 + (((k + 2) * 14) << 6);    // h' = h + (k_idx+2)
    unsigned char* zo = ztwk + (size_t)k * 10752 * 256;

    const int tid = threadIdx.x;
    const unsigned char* zsrc = (const unsigned char*)(zt + (size_t)zrow0 * 256);
    const unsigned char* bsrc = (const unsigned char*)(wkb + ((size_t)k << 16) + o0 * 256);

    #pragma unroll
    for (int i = 0; i < 8; ++i) {          // A: 32 KB contiguous
        int sb = ((i << 8) + tid) << 4;
        int r = sb >> 9, off = sb & 511;
        *(int4*)(smA + r * PSTR + off) = *(const int4*)(zsrc + sb);
    }
    #pragma unroll
    for (int i = 0; i < 4; ++i) {          // B: 16 KB contiguous
        int sb = ((i << 8) + tid) << 4;
        int r = sb >> 9, off = sb & 511;
        *(int4*)(smB + r * PSTR + off) = *(const int4*)(bsrc + sb);
    }
    __syncthreads();

    const int wv = tid >> 6, lane = tid & 63;
    const int m = lane & 15, kq = lane >> 4;
    f32x4 acc[2] = {};
    const unsigned short* aP  = (const unsigned short*)(smA + (size_t)((wv << 4) + m) * PSTR) + (kq << 3);
    const unsigned short* bP0 = (const unsigned short*)(smB + (size_t)m * PSTR) + (kq << 3);
    const unsigned short* bP1 = (const unsigned short*)(smB + (size_t)(16 + m) * PSTR) + (kq << 3);
    #pragma unroll
    for (int kk = 0; kk < 256; kk += 32) {
        bf16x8 af = *(const bf16x8*)(aP  + kk);
        bf16x8 b0 = *(const bf16x8*)(bP0 + kk);
        bf16x8 b1 = *(const bf16x8*)(bP1 + kk);
        acc[0] = __builtin_amdgcn_mfma_f32_16x16x32_bf16(af, b0, acc[0], 0, 0, 0);
        acc[1] = __builtin_amdgcn_mfma_f32_16x16x32_bf16(af, b1, acc[1], 0, 0, 0);
    }
    __syncthreads();
    unsigned char* cs = smA;               // [64 rows][40 B]
    #pragma unroll
    for (int nt = 0; nt < 2; ++nt)
        #pragma unroll
        for (int r = 0; r < 4; ++r)
            cs[(size_t)((wv << 4) + (kq << 2) + r) * 40 + (nt << 4) + m] =
                f2e4m3(acc[nt][r]);
    __syncthreads();
    {
        int r = tid >> 2, off = (tid & 3) << 3;
        unsigned long long v = *(const unsigned long long*)(cs + (size_t)r * 40 + off);
        *(unsigned long long*)(zo + (size_t)(row0 + r) * 256 + o0 + off) = v;
    }
}

// loss: one block (2 waves) per row. Slots: 0 main, 1..64 negs (stride 256),
// 65..67 junk. Gather: 17x global_load_lds size=16 (4 slots/instr, per-lane
// source row via __shfl of the coalesced idx load) + 1 ctx DMA. Both-sides
// XOR swizzle ((slot&7)<<4, 16B granule) keeps fragment ds_read_b64 2-way.
__global__ __launch_bounds__(128, 4)
void loss_mfma_kernel(const unsigned char* __restrict__ ct8,
                      const unsigned char* __restrict__ ztwk8,
                      const int* __restrict__ n0, const int* __restrict__ n1,
                      const int* __restrict__ n2, float* __restrict__ rowloss) {
    __shared__ __align__(16) unsigned char slab[68 * 256];   // 17408 B
    __shared__ __align__(16) unsigned char ctx_s[256];
    __shared__ float sred[2][2];
    const int tid = threadIdx.x;
    const int wv = tid >> 6, lane = tid & 63;
    const int m = lane & 15, kq = lane >> 4;

    int x = blockIdx.x;
    int k; const int* nb_base;
    if (x < 10752)      { k = 0; nb_base = n0; }
    else if (x < 20608) { k = 1; nb_base = n1; x -= 10752; }
    else                { k = 2; nb_base = n2; x -= 20608; }
    const int row = x;
    const unsigned char* flat8 = ztwk8 + (size_t)k * 10752 * 256;
    const float wk = (k == 0) ? (1.f / (3.f * 10752.f))
                   : (k == 1) ? (1.f / (3.f * 9856.f))
                              : (1.f / (3.f * 8960.f));
    const int rbase = (k == 0) ? 0 : (k == 1) ? 10752 : 20608;

    const int myidx = nb_base[((size_t)row << 6) + lane];   // coalesced 256B
    const int lg = lane >> 4;          // lane group -> slot within instr
    const int d  = (lane & 15) << 4;   // 16B block within slot

    if (wv == 0) {
        #pragma unroll
        for (int j = 0; j < 9; ++j) {            // slots 0..35 (no clamp)
            int slot = (j << 2) + lg;
            int sel = slot - 1; if (sel < 0) sel = 0;
            int srow = __shfl(myidx, sel);
            if (slot == 0) srow = row;           // slot 0 = main row
            gload_lds16(flat8 + (size_t)srow * 256 + (d ^ ((slot & 7) << 4)),
                        slab + (j << 10));
        }
    } else {
        gload_lds4(ct8 + (size_t)row * 256 + (lane << 2), ctx_s);
        #pragma unroll
        for (int j = 9; j < 17; ++j) {           // slots 36..67 (clamp at 64)
            int slot = (j << 2) + lg;
            int sc = slot > 64 ? 64 : slot;
            int srow = __shfl(myidx, sc - 1);
            gload_lds16(flat8 + (size_t)srow * 256 + (d ^ ((sc & 7) << 4)),
                        slab + (j << 10));
        }
    }
    __syncthreads();   // drains vmcnt (DMA) for the whole block

    f32x4 acc[3] = {};
    const int mt0 = (wv == 0) ? 0 : 3;
    int soff[3];
    #pragma unroll
    for (int t = 0; t < 3; ++t) {
        int slot = ((mt0 + t) << 4) + m;
        if (slot > 64) slot = 64;
        soff[t] = (slot << 8) + ((kq << 3) ^ ((slot & 7) << 4));
    }
    const unsigned char* cp = ctx_s + (kq << 3);
    #pragma unroll
    for (int kk = 0; kk < 8; ++kk) {
        long long bfrag = *(const long long*)(cp + (kk << 5));
        #pragma unroll
        for (int t = 0; t < 3; ++t) {
            if (t < 2 || wv == 0) {
                long long af = *(const long long*)(slab + (soff[t] ^ (kk << 5)));
                acc[t] = __builtin_amdgcn_mfma_f32_16x16x32_fp8_fp8(af, bfrag, acc[t], 0, 0, 0);
            }
        }
    }

    float m_l = -1e30f;
    if (wv == 0) {
        #pragma unroll
        for (int t = 0; t < 3; ++t)
            #pragma unroll
            for (int r = 0; r < 4; ++r) m_l = fmaxf(m_l, acc[t][r]);
    } else {
        #pragma unroll
        for (int r = 0; r < 4; ++r) m_l = fmaxf(m_l, acc[0][r]);   // mt=3
        if (kq == 0) m_l = fmaxf(m_l, acc[1][0]);                  // slot 64
    }
    m_l = fmaxf(m_l, __shfl_xor(m_l, 16));
    m_l = fmaxf(m_l, __shfl_xor(m_l, 32));

    float s_l = 0.f;
    if (wv == 0) {
        #pragma unroll
        for (int t = 0; t < 3; ++t)
            #pragma unroll
            for (int r = 0; r < 4; ++r) s_l += __expf(acc[t][r] - m_l);
    } else {
        #pragma unroll
        for (int r = 0; r < 4; ++r) s_l += __expf(acc[0][r] - m_l);
        if (kq == 0) s_l += __expf(acc[1][0] - m_l);
    }
    s_l += __shfl_xor(s_l, 16);
    s_l += __shfl_xor(s_l, 32);

    float main_l = acc[0][0];   // valid at wv0 lane0 (slot 0)
    if (lane == 0) { sred[wv][0] = m_l; sred[wv][1] = s_l; }
    __syncthreads();
    if (tid == 0) {
        float m0 = sred[0][0], s0 = sred[0][1];
        float m1 = sred[1][0], s1 = sred[1][1];
        float mg = fmaxf(m0, m1);
        float sg = s0 * __expf(m0 - mg) + s1 * __expf(m1 - mg);
        float p0 = __expf(main_l - mg) / sg;
        rowloss[rbase + row] = -logf(p0 + 1e-11f) * wk;
    }
}

// Sum rowloss[0..29568) -> out[0] (out zeroed in prep)
__global__ __launch_bounds__(256)
void reduce_kernel(const float* __restrict__ rl, float* __restrict__ out) {
    float s = 0.f;
    const int stride = gridDim.x * blockDim.x;
    for (int i = blockIdx.x * blockDim.x + threadIdx.x; i < 29568; i += stride)
        s += rl[i];
    #pragma unroll
    for (int off = 32; off >= 1; off >>= 1) s += __shfl_xor(s, off);
    if ((threadIdx.x & 63) == 0) atomicAdd(out, s);
}

extern "C" void kernel_launch(void* const* d_in, const int* in_sizes, int n_in,
                              void* d_out, int out_size, void* d_ws, size_t ws_size,
                              hipStream_t stream) {
    const float* z  = (const float*)d_in[0];
    const float* c  = (const float*)d_in[1];
    const float* Wk = (const float*)d_in[2];
    const int* negs[3] = {(const int*)d_in[3], (const int*)d_in[4], (const int*)d_in[5]};
    float* out = (float*)d_out;

    char* p = (char*)d_ws;
    unsigned short* zt      = (unsigned short*)p;   p += (size_t)196 * 64 * 256 * 2;
    unsigned short* wkb     = (unsigned short*)p;   p += (size_t)3 * 65536 * 2;
    unsigned char*  ct8     = (unsigned char*)p;    p += (size_t)196 * 64 * 256;
    unsigned char*  ztwk8   = (unsigned char*)p;    p += (size_t)3 * 10752 * 256;
    float*          rowloss = (float*)p;

    prep_kernel<<<2816, 256, 0, stream>>>(z, c, Wk, zt, ct8, wkb, out);
    proj_mfma_kernel<<<dim3(8, 462), 256, 0, stream>>>(zt, wkb, ztwk8);
    loss_mfma_kernel<<<29568, 128, 0, stream>>>(ct8, ztwk8, negs[0], negs[1],
                                                negs[2], rowloss);
    reduce_kernel<<<32, 256, 0, stream>>>(rowloss, out);
}

// Round 7
// 149.455 us; speedup vs baseline: 1.1542x; 1.0236x over previous
//
#include <hip/hip_runtime.h>
#include <math.h>

// InfoNCE loss, K=3, SKIP=1, NEG=64
// z,c: (64,256,14,14) f32; Wk: (3,256,256) f32; neg_idx_k: (rows_k*64,) i32
// rows_k = 10752, 9856, 8960. row = (h*14+w)*64 + b.
//
// Pipeline (4 launches): prep (LDS-free transpose, wide stores), proj
// (64x64-tile LDS-staged bf16 MFMA GEMM -> ztwk fp8: 1848 blocks, A+B each
// staged ONCE per block -- the old 3696-block version re-staged A 8x),
// loss (R2-verbatim wide-DMA gather, ~49us = chip random-gather service
// rate ~10 TB/s: 4 structurally different implementations all converge
// there with no CU-side counter saturated), reduce.

typedef short bf16x8 __attribute__((ext_vector_type(8)));
typedef float f32x4 __attribute__((ext_vector_type(4)));

static __device__ __forceinline__ unsigned short f2bf(float f) {
    union { float f; unsigned int u; } x; x.f = f;
    unsigned int r = x.u + 0x7fffu + ((x.u >> 16) & 1u);   // RNE
    return (unsigned short)(r >> 16);
}

// float -> OCP e4m3fn (RNE, saturate to 448, subnormals handled)
static __device__ __forceinline__ unsigned char f2e4m3(float f) {
    union { float f; unsigned int u; } x; x.f = f;
    unsigned int s = (x.u >> 24) & 0x80u;
    float af = fabsf(f);
    if (af > 448.f) af = 448.f;
    x.f = af;
    unsigned int u = x.u;
    int e = (int)(u >> 23) - 127;
    unsigned int out;
    if (af == 0.f) {
        out = 0u;
    } else if (e < -6) {
        int mq = (int)rintf(af * 512.f);          // multiples of 2^-9
        out = (mq >= 8) ? 0x08u : (unsigned int)mq;
    } else {
        unsigned int r = u + 0x7FFFFu + ((u >> 20) & 1u);  // RNE, drop 20 bits
        int e2 = (int)(r >> 23) - 127;
        if (e2 > 8) out = 0x7Eu;                  // 448
        else out = (unsigned int)(((e2 + 7) << 3) | ((r >> 20) & 7u));
    }
    return (unsigned char)(s | out);
}

// async global->LDS DMA: per-lane global addr, dest = uniform base + lane*sz
static __device__ __forceinline__ void gload_lds4(const void* g, void* l) {
    __builtin_amdgcn_global_load_lds(
        (const __attribute__((address_space(1))) void*)g,
        (__attribute__((address_space(3))) void*)l, 4, 0, 0);
}
static __device__ __forceinline__ void gload_lds16(const void* g, void* l) {
    __builtin_amdgcn_global_load_lds(
        (const __attribute__((address_space(1))) void*)g,
        (__attribute__((address_space(3))) void*)l, 16, 0, 0);
}

// prep: blocks [0,768): Wk->bf16 (block0 also zeroes out[0]);
// [768,1792): z -> zt bf16 transposed; [1792,2816): c -> ct8 fp8 transposed.
// z/c path: thread hw (0..195) loads 16 channels via lane-coalesced dword
// loads, packs in regs, stores wide. No LDS, no barrier.
__global__ __launch_bounds__(256)
void prep_kernel(const float* __restrict__ z, const float* __restrict__ c,
                 const float* __restrict__ Wk,
                 unsigned short* __restrict__ zt, unsigned char* __restrict__ ct8,
                 unsigned short* __restrict__ wkb, float* __restrict__ out) {
    const int tid = threadIdx.x;
    int x = blockIdx.x;
    if (x < 768) {
        int i = x * 256 + tid;
        wkb[i] = f2bf(Wk[i]);
        if (x == 0 && tid == 0) out[0] = 0.f;
        return;
    }
    const bool isz = x < 1792;
    const int local = isz ? (x - 768) : (x - 1792);
    const float* src = isz ? z : c;
    const int b  = local & 63;
    const int c0 = (local >> 6) << 4;
    if (tid >= 196) return;
    const int hw = tid;

    float v[16];
    #pragma unroll
    for (int cc = 0; cc < 16; ++cc)
        v[cc] = src[(size_t)((b << 8) + c0 + cc) * 196 + hw];

    if (isz) {
        union { unsigned short u[16]; int4 q[2]; } pk;
        #pragma unroll
        for (int cc = 0; cc < 16; ++cc) pk.u[cc] = f2bf(v[cc]);
        unsigned short* dst = zt + (size_t)((hw << 6) + b) * 256 + c0;
        *(int4*)(dst)     = pk.q[0];
        *(int4*)(dst + 8) = pk.q[1];
    } else {
        union { unsigned char u[16]; int4 q; } pk;
        #pragma unroll
        for (int cc = 0; cc < 16; ++cc) pk.u[cc] = f2e4m3(v[cc]);
        *(int4*)(ct8 + (size_t)((hw << 6) + b) * 256 + c0) = pk.q;
    }
}

// proj: ztwk8[k][row][o] = fp8(sum_c zt[zrow][c] * wk[k][o][c])
// Grid (4, 462): 64x64 output tile per block; A (64 rows) and B (64 outs)
// each staged ONCE. o-tile is blockIdx.x (FAST) so the 4 o-tiles of one
// hw-tile dispatch consecutively -> A stays L2-hot. PSTR 528: dword stride
// 132 == 4 (mod 32) -> 2-way frag-read banking (free).
#define PSTR 528
__global__ __launch_bounds__(256)
void proj_mfma_kernel(const unsigned short* __restrict__ zt,
                      const unsigned short* __restrict__ wkb,
                      unsigned char* __restrict__ ztwk) {
    __shared__ __align__(16) unsigned char smem[(64 + 64) * PSTR];  // 67584 B
    unsigned char* smA = smem;
    unsigned char* smB = smem + 64 * PSTR;

    int x = blockIdx.y;
    int k, hw;
    if (x < 168)      { k = 0; hw = x; }
    else if (x < 322) { k = 1; hw = x - 168; }
    else              { k = 2; hw = x - 322; }
    const int o0 = blockIdx.x << 6;                    // 64 outs per block
    const int row0  = hw << 6;
    const int zrow0 = row0 + (((k + 2) * 14) << 6);    // h' = h + (k_idx+2)
    unsigned char* zo = ztwk + (size_t)k * 10752 * 256;

    const int tid = threadIdx.x;
    const unsigned char* zsrc = (const unsigned char*)(zt + (size_t)zrow0 * 256);
    const unsigned char* bsrc = (const unsigned char*)(wkb + ((size_t)k << 16) + o0 * 256);

    #pragma unroll
    for (int i = 0; i < 8; ++i) {          // A: 32 KB contiguous
        int sb = ((i << 8) + tid) << 4;
        int r = sb >> 9, off = sb & 511;
        *(int4*)(smA + r * PSTR + off) = *(const int4*)(zsrc + sb);
    }
    #pragma unroll
    for (int i = 0; i < 8; ++i) {          // B: 32 KB contiguous
        int sb = ((i << 8) + tid) << 4;
        int r = sb >> 9, off = sb & 511;
        *(int4*)(smB + r * PSTR + off) = *(const int4*)(bsrc + sb);
    }
    __syncthreads();

    const int wv = tid >> 6, lane = tid & 63;
    const int m = lane & 15, kq = lane >> 4;
    f32x4 acc[4] = {};
    const unsigned short* aP = (const unsigned short*)(smA + (size_t)((wv << 4) + m) * PSTR) + (kq << 3);
    #pragma unroll
    for (int kk = 0; kk < 256; kk += 32) {
        bf16x8 af = *(const bf16x8*)(aP + kk);
        #pragma unroll
        for (int nt = 0; nt < 4; ++nt) {
            const unsigned short* bP =
                (const unsigned short*)(smB + (size_t)((nt << 4) + m) * PSTR) + (kq << 3);
            bf16x8 bfr = *(const bf16x8*)(bP + kk);
            acc[nt] = __builtin_amdgcn_mfma_f32_16x16x32_bf16(af, bfr, acc[nt], 0, 0, 0);
        }
    }
    __syncthreads();
    unsigned char* cs = smA;               // [64 rows][80 B]
    #pragma unroll
    for (int nt = 0; nt < 4; ++nt)
        #pragma unroll
        for (int r = 0; r < 4; ++r)
            cs[(size_t)((wv << 4) + (kq << 2) + r) * 80 + (nt << 4) + m] =
                f2e4m3(acc[nt][r]);
    __syncthreads();
    {
        int r = tid >> 2, off = (tid & 3) << 4;
        int4 v = *(const int4*)(cs + (size_t)r * 80 + off);
        *(int4*)(zo + (size_t)(row0 + r) * 256 + o0 + off) = v;
    }
}

// loss: one block (2 waves) per row. Slots: 0 main, 1..64 negs (stride 256),
// 65..67 junk. Gather: 17x global_load_lds size=16 (4 slots/instr, per-lane
// source row via __shfl of the coalesced idx load) + 1 ctx DMA. Both-sides
// XOR swizzle ((slot&7)<<4, 16B granule) keeps fragment ds_read_b64 2-way.
__global__ __launch_bounds__(128, 4)
void loss_mfma_kernel(const unsigned char* __restrict__ ct8,
                      const unsigned char* __restrict__ ztwk8,
                      const int* __restrict__ n0, const int* __restrict__ n1,
                      const int* __restrict__ n2, float* __restrict__ rowloss) {
    __shared__ __align__(16) unsigned char slab[68 * 256];   // 17408 B
    __shared__ __align__(16) unsigned char ctx_s[256];
    __shared__ float sred[2][2];
    const int tid = threadIdx.x;
    const int wv = tid >> 6, lane = tid & 63;
    const int m = lane & 15, kq = lane >> 4;

    int x = blockIdx.x;
    int k; const int* nb_base;
    if (x < 10752)      { k = 0; nb_base = n0; }
    else if (x < 20608) { k = 1; nb_base = n1; x -= 10752; }
    else                { k = 2; nb_base = n2; x -= 20608; }
    const int row = x;
    const unsigned char* flat8 = ztwk8 + (size_t)k * 10752 * 256;
    const float wk = (k == 0) ? (1.f / (3.f * 10752.f))
                   : (k == 1) ? (1.f / (3.f * 9856.f))
                              : (1.f / (3.f * 8960.f));
    const int rbase = (k == 0) ? 0 : (k == 1) ? 10752 : 20608;

    const int myidx = nb_base[((size_t)row << 6) + lane];   // coalesced 256B
    const int lg = lane >> 4;          // lane group -> slot within instr
    const int d  = (lane & 15) << 4;   // 16B block within slot

    if (wv == 0) {
        #pragma unroll
        for (int j = 0; j < 9; ++j) {            // slots 0..35 (no clamp)
            int slot = (j << 2) + lg;
            int sel = slot - 1; if (sel < 0) sel = 0;
            int srow = __shfl(myidx, sel);
            if (slot == 0) srow = row;           // slot 0 = main row
            gload_lds16(flat8 + (size_t)srow * 256 + (d ^ ((slot & 7) << 4)),
                        slab + (j << 10));
        }
    } else {
        gload_lds4(ct8 + (size_t)row * 256 + (lane << 2), ctx_s);
        #pragma unroll
        for (int j = 9; j < 17; ++j) {           // slots 36..67 (clamp at 64)
            int slot = (j << 2) + lg;
            int sc = slot > 64 ? 64 : slot;
            int srow = __shfl(myidx, sc - 1);
            gload_lds16(flat8 + (size_t)srow * 256 + (d ^ ((sc & 7) << 4)),
                        slab + (j << 10));
        }
    }
    __syncthreads();   // drains vmcnt (DMA) for the whole block

    f32x4 acc[3] = {};
    const int mt0 = (wv == 0) ? 0 : 3;
    int soff[3];
    #pragma unroll
    for (int t = 0; t < 3; ++t) {
        int slot = ((mt0 + t) << 4) + m;
        if (slot > 64) slot = 64;
        soff[t] = (slot << 8) + ((kq << 3) ^ ((slot & 7) << 4));
    }
    const unsigned char* cp = ctx_s + (kq << 3);
    #pragma unroll
    for (int kk = 0; kk < 8; ++kk) {
        long long bfrag = *(const long long*)(cp + (kk << 5));
        #pragma unroll
        for (int t = 0; t < 3; ++t) {
            if (t < 2 || wv == 0) {
                long long af = *(const long long*)(slab + (soff[t] ^ (kk << 5)));
                acc[t] = __builtin_amdgcn_mfma_f32_16x16x32_fp8_fp8(af, bfrag, acc[t], 0, 0, 0);
            }
        }
    }

    float m_l = -1e30f;
    if (wv == 0) {
        #pragma unroll
        for (int t = 0; t < 3; ++t)
            #pragma unroll
            for (int r = 0; r < 4; ++r) m_l = fmaxf(m_l, acc[t][r]);
    } else {
        #pragma unroll
        for (int r = 0; r < 4; ++r) m_l = fmaxf(m_l, acc[0][r]);   // mt=3
        if (kq == 0) m_l = fmaxf(m_l, acc[1][0]);                  // slot 64
    }
    m_l = fmaxf(m_l, __shfl_xor(m_l, 16));
    m_l = fmaxf(m_l, __shfl_xor(m_l, 32));

    float s_l = 0.f;
    if (wv == 0) {
        #pragma unroll
        for (int t = 0; t < 3; ++t)
            #pragma unroll
            for (int r = 0; r < 4; ++r) s_l += __expf(acc[t][r] - m_l);
    } else {
        #pragma unroll
        for (int r = 0; r < 4; ++r) s_l += __expf(acc[0][r] - m_l);
        if (kq == 0) s_l += __expf(acc[1][0] - m_l);
    }
    s_l += __shfl_xor(s_l, 16);
    s_l += __shfl_xor(s_l, 32);

    float main_l = acc[0][0];   // valid at wv0 lane0 (slot 0)
    if (lane == 0) { sred[wv][0] = m_l; sred[wv][1] = s_l; }
    __syncthreads();
    if (tid == 0) {
        float m0 = sred[0][0], s0 = sred[0][1];
        float m1 = sred[1][0], s1 = sred[1][1];
        float mg = fmaxf(m0, m1);
        float sg = s0 * __expf(m0 - mg) + s1 * __expf(m1 - mg);
        float p0 = __expf(main_l - mg) / sg;
        rowloss[rbase + row] = -logf(p0 + 1e-11f) * wk;
    }
}

// Sum rowloss[0..29568) -> out[0] (out zeroed in prep)
__global__ __launch_bounds__(256)
void reduce_kernel(const float* __restrict__ rl, float* __restrict__ out) {
    float s = 0.f;
    const int stride = gridDim.x * blockDim.x;
    for (int i = blockIdx.x * blockDim.x + threadIdx.x; i < 29568; i += stride)
        s += rl[i];
    #pragma unroll
    for (int off = 32; off >= 1; off >>= 1) s += __shfl_xor(s, off);
    if ((threadIdx.x & 63) == 0) atomicAdd(out, s);
}

extern "C" void kernel_launch(void* const* d_in, const int* in_sizes, int n_in,
                              void* d_out, int out_size, void* d_ws, size_t ws_size,
                              hipStream_t stream) {
    const float* z  = (const float*)d_in[0];
    const float* c  = (const float*)d_in[1];
    const float* Wk = (const float*)d_in[2];
    const int* negs[3] = {(const int*)d_in[3], (const int*)d_in[4], (const int*)d_in[5]};
    float* out = (float*)d_out;

    char* p = (char*)d_ws;
    unsigned short* zt      = (unsigned short*)p;   p += (size_t)196 * 64 * 256 * 2;
    unsigned short* wkb     = (unsigned short*)p;   p += (size_t)3 * 65536 * 2;
    unsigned char*  ct8     = (unsigned char*)p;    p += (size_t)196 * 64 * 256;
    unsigned char*  ztwk8   = (unsigned char*)p;    p += (size_t)3 * 10752 * 256;
    float*          rowloss = (float*)p;

    prep_kernel<<<2816, 256, 0, stream>>>(z, c, Wk, zt, ct8, wkb, out);
    proj_mfma_kernel<<<dim3(4, 462), 256, 0, stream>>>(zt, wkb, ztwk8);
    loss_mfma_kernel<<<29568, 128, 0, stream>>>(ct8, ztwk8, negs[0], negs[1],
                                                negs[2], rowloss);
    reduce_kernel<<<32, 256, 0, stream>>>(rowloss, out);
}